// Round 6
// baseline (432.802 us; speedup 1.0000x reference)
//
#include <hip/hip_runtime.h>
#include <math.h>

#define IMG 401
#define NKP 17
#define NMID 32
#define CCH 150   // coarse channels: 0-16 kp(sig) | 17-50 so | 51-114 mo | 115-148 lo | 149 ss(sig)

// output region element offsets (f32 elements); P = 2*401*401 = 321602 pixels
#define OFF_KP   0ULL
#define OFF_SO   5467234ULL
#define OFF_MID  16401702ULL
#define OFF_LONG 36984230ULL
#define OFF_SS   47918698ULL
// total out_size = 48,240,300 f32

#define SCc (13.0f/401.0f)
#define C0c (13.0f/802.0f - 0.5f)

// statics: rewritten fully every call before being read
__device__ float  g_coarse[2 * 169 * CCH];
// field-planar pairs: [n][66 fields][169 cells] float2; fields 0-16=so,17-48=mo,49-65=lo
__device__ float2 g_pairs[2 * 66 * 169];

__constant__ int TO_KP_C[32] = {1,3,2,4,5,7,9,11,13,15,6,8,10,12,14,16,
                                0,1,0,2,0,5,7,5,11,13,0,6,8,6,12,14};

__device__ __forceinline__ void store2(float* p, float a, float b) {
  *reinterpret_cast<float2*>(p) = make_float2(a, b);   // 8B-aligned by construction
}

// ---------------- kernel 1: heads GEMM (x[338,2048] @ W -> coarse + pairs) ----------
__global__ __launch_bounds__(256)
void heads_kernel(const float* __restrict__ x,
                  const float* __restrict__ kp_w, const float* __restrict__ kp_b,
                  const float* __restrict__ so_w, const float* __restrict__ so_b,
                  const float* __restrict__ mo_w, const float* __restrict__ mo_b,
                  const float* __restrict__ lo_w, const float* __restrict__ lo_b,
                  const float* __restrict__ ss_w, const float* __restrict__ ss_b) {
  __shared__ float xs[2048];
  const int pix = blockIdx.x;                 // 0..337  (= n*169 + p)
  const float* xr = x + (size_t)pix * 2048;
  for (int t = threadIdx.x; t < 2048; t += 256) xs[t] = xr[t];
  __syncthreads();
  const int c = threadIdx.x;
  if (c >= CCH) return;
  const float* wptr; const float* bptr; int Ch, cc; bool sig = false;
  if (c < 17)       { wptr = kp_w; bptr = kp_b; Ch = 17; cc = c;       sig = true; }
  else if (c < 51)  { wptr = so_w; bptr = so_b; Ch = 34; cc = c - 17; }
  else if (c < 115) { wptr = mo_w; bptr = mo_b; Ch = 64; cc = c - 51; }
  else if (c < 149) { wptr = lo_w; bptr = lo_b; Ch = 34; cc = c - 115; }
  else              { wptr = ss_w; bptr = ss_b; Ch = 1;  cc = 0;       sig = true; }
  float acc = bptr[cc];
  const float* wp = wptr + cc;
  #pragma unroll 8
  for (int k = 0; k < 2048; ++k) acc = fmaf(xs[k], wp[k * Ch], acc);
  if (sig) acc = 1.0f / (1.0f + expf(-acc));
  g_coarse[(size_t)pix * CCH + c] = acc;
  if (c >= 17 && c < 149) {
    int rel = c - 17;
    int nn = pix / 169, pp = pix - nn * 169;
    ((float*)g_pairs)[(((size_t)nn * 66 + (rel >> 1)) * 169 + pp) * 2 + (rel & 1)] = acc;
  }
}

// ------------- fine-grid index -> coarse cell map (jax.image.resize bilinear, clamped) ----
__device__ __forceinline__ void cmapf(int j, int& i0, int& i1, float& f) {
  float s  = fmaf((float)j, SCc, C0c);
  float fl = floorf(s);
  f = s - fl;
  int a = (int)fl, b = a + 1;
  i0 = a < 0 ? 0 : (a > 12 ? 12 : a);
  i1 = b < 0 ? 0 : (b > 12 ? 12 : b);
}

__device__ __forceinline__ float2 blp4(const float2* __restrict__ F,
                                       int i00, int i01, int i10, int i11,
                                       float u, float v) {
  float2 a = F[i00], b = F[i01], c = F[i10], d = F[i11];
  float w00 = (1.f - u) * (1.f - v), w01 = u * (1.f - v);
  float w10 = (1.f - u) * v,         w11 = u * v;
  return make_float2(w00 * a.x + w01 * b.x + w10 * c.x + w11 * d.x,
                     w00 * a.y + w01 * b.y + w10 * c.y + w11 * d.y);
}

// ----- one bilinear_sampler evaluation on resized field F (13x13 coarse in LDS) -----
__device__ __forceinline__ float2 sampleF(const float2* __restrict__ F, float2 base, int w, int h) {
  float vx = base.x, vy = base.y;
  float fx0 = floorf(vx), fy0 = floorf(vy);
  float dx = vx - fx0,    dy = vy - fy0;
  int jx0 = (int)fx0 + w, jy0 = (int)fy0 + h;
  int jx1 = jx0 + (dx > 0.f ? 1 : 0), jy1 = jy0 + (dy > 0.f ? 1 : 0);
  if (jx0 < 0 || jy0 < 0 || jx1 > 400 || jy1 > 400) return make_float2(0.f, 0.f);
  // coarse-space positions of the 4 fine corners (shared by fast & slow paths)
  float s0x = fmaf((float)jx0, SCc, C0c), s1x = fmaf((float)jx1, SCc, C0c);
  float s0y = fmaf((float)jy0, SCc, C0c), s1y = fmaf((float)jy1, SCc, C0c);
  float c0x = floorf(s0x), c1x = floorf(s1x);
  float c0y = floorf(s0y), c1y = floorf(s1y);
  if (c0x == c1x && c0y == c1y &&
      c0x >= 0.f && c0x <= 11.f && c0y >= 0.f && c0y <= 11.f) {
    // interior same-cell: bilerp-of-bilerp collapses to one bilerp at averaged fracs
    float fxa = s0x - c0x, fya = s0y - c0y;
    float u = fxa + dx * (s1x - s0x);
    float v = fya + dy * (s1y - s0y);
    int i = (int)c0y * 13 + (int)c0x;
    return blp4(F, i, i + 1, i + 13, i + 14, u, v);
  }
  // slow path: exact cmapf semantics reconstructed from the shared s/c values
  int ax = (int)c0x, bx = (int)c1x, ay = (int)c0y, by = (int)c1y;
  float fxa = s0x - c0x, fxb = s1x - c1x, fya = s0y - c0y, fyb = s1y - c1y;
  int xa0 = min(max(ax, 0), 12),     xa1 = min(max(ax + 1, 0), 12);
  int xb0 = min(max(bx, 0), 12),     xb1 = min(max(bx + 1, 0), 12);
  int ya0 = min(max(ay, 0), 12),     ya1 = min(max(ay + 1, 0), 12);
  int yb0 = min(max(by, 0), 12),     yb1 = min(max(by + 1, 0), 12);
  float2 a00 = blp4(F, ya0*13+xa0, ya0*13+xa1, ya1*13+xa0, ya1*13+xa1, fxa, fya);
  float2 a01 = blp4(F, yb0*13+xa0, yb0*13+xa1, yb1*13+xa0, yb1*13+xa1, fxa, fyb);
  float2 a10 = blp4(F, ya0*13+xb0, ya0*13+xb1, ya1*13+xb0, ya1*13+xb1, fxb, fya);
  float2 a11 = blp4(F, yb0*13+xb0, yb0*13+xb1, yb1*13+xb0, yb1*13+xb1, fxb, fyb);
  float w00 = (1.f - dx) * (1.f - dy), w01 = (1.f - dx) * dy;
  float w10 = dx * (1.f - dy),         w11 = dx * dy;
  return make_float2(w00*a00.x + w01*a01.x + w10*a10.x + w11*a11.x,
                     w00*a00.y + w01*a01.y + w10*a10.y + w11*a11.y);
}

// ---------------- kernel 2: kp + so + ss, element-parallel fully-coalesced bilerp --------
__global__ __launch_bounds__(256)
void ksos_kernel(float* __restrict__ out) {
  for (long long idx = (long long)blockIdx.x * 256 + threadIdx.x; idx < 16723304LL;
       idx += (long long)gridDim.x * 256) {
    int pix, src; long long oidx = idx;
    if (idx < 5467234LL) {
      unsigned i = (unsigned)idx; pix = i / 17u; src = i - (unsigned)pix * 17u;
    } else if (idx < 16401702LL) {
      unsigned r = (unsigned)(idx - 5467234LL); pix = r / 34u; src = 17 + (r - (unsigned)pix * 34u);
    } else {
      pix = (int)(idx - 16401702LL); src = 149; oidx = (long long)OFF_SS + (idx - 16401702LL);
    }
    unsigned up = (unsigned)pix;
    int w = up % 401u; unsigned t = up / 401u; int h = t % 401u; int n = t / 401u;
    int px0, px1, py0, py1; float fx, fy;
    cmapf(w, px0, px1, fx);
    cmapf(h, py0, py1, fy);
    const float* cb = g_coarse + (size_t)n * 169 * CCH;
    float v00 = cb[(py0*13+px0)*CCH + src], v01 = cb[(py0*13+px1)*CCH + src];
    float v10 = cb[(py1*13+px0)*CCH + src], v11 = cb[(py1*13+px1)*CCH + src];
    float q00 = (1.f-fx)*(1.f-fy), q01 = fx*(1.f-fy), q10 = (1.f-fx)*fy, q11 = fx*fy;
    out[oidx] = q00*v00 + q01*v01 + q10*v10 + q11*v11;
  }
}

// ---------------- kernel 3: long + mid refinement (512-thread, single-round) -------------
__global__ __launch_bounds__(512, 6)
void refine512_kernel(float* __restrict__ out) {
  __shared__ float2 Sf[NKP * 169];
  __shared__ float2 Lf[NKP * 169];
  const int n = blockIdx.z;
  const int tid = threadIdx.y * 32 + threadIdx.x;
  for (int t = tid; t < NKP * 169; t += 512) {
    int k = t / 169, p = t - k * 169;
    Sf[t] = g_pairs[((size_t)n * 66 + k) * 169 + p];
    Lf[t] = g_pairs[((size_t)n * 66 + 49 + k) * 169 + p];
  }
  __syncthreads();
  const int w = blockIdx.x * 32 + threadIdx.x;
  const int h = blockIdx.y * 16 + threadIdx.y;
  if (w >= IMG || h >= IMG) return;

  int px0, px1, py0, py1; float pfx, pfy;
  cmapf(w, px0, px1, pfx);
  cmapf(h, py0, py1, pfy);
  const float q00 = (1.f-pfx)*(1.f-pfy), q01 = pfx*(1.f-pfy);
  const float q10 = (1.f-pfx)*pfy,       q11 = pfx*pfy;
  const int i00 = py0*13+px0, i01 = py0*13+px1, i10 = py1*13+px0, i11 = py1*13+px1;
  const size_t pix = ((size_t)n * IMG + h) * IMG + w;

  // long: refine(refine(L,L), S) -> 34 ch
  float* olg = out + OFF_LONG + pix * 34;
  for (int k = 0; k < NKP; ++k) {
    const float2* S = &Sf[k * 169];
    const float2* L = &Lf[k * 169];
    float2 b = blp4(L, i00, i01, i10, i11, pfx, pfy);
    float2 d;
    d = sampleF(L, b, w, h); b.x += d.x; b.y += d.y;
    d = sampleF(L, b, w, h); b.x += d.x; b.y += d.y;
    d = sampleF(S, b, w, h); b.x += d.x; b.y += d.y;
    d = sampleF(S, b, w, h); b.x += d.x; b.y += d.y;
    store2(olg + 2 * k, b.x, b.y);
  }

  // mid: refine(M, S[to_kp]) -> 64 ch
  float* omd = out + OFF_MID + pix * 64;
  const float2* gmo = g_pairs + ((size_t)n * 66 + 17) * 169;
  for (int g = 0; g < NMID; ++g) {
    const float2* G = gmo + (size_t)g * 169;
    float2 e00 = G[i00], e01 = G[i01], e10 = G[i10], e11 = G[i11];
    float2 b = make_float2(q00*e00.x + q01*e01.x + q10*e10.x + q11*e11.x,
                           q00*e00.y + q01*e01.y + q10*e10.y + q11*e11.y);
    const float2* S = &Sf[TO_KP_C[g] * 169];
    float2 d;
    d = sampleF(S, b, w, h); b.x += d.x; b.y += d.y;
    d = sampleF(S, b, w, h); b.x += d.x; b.y += d.y;
    store2(omd + 2 * g, b.x, b.y);
  }
}

extern "C" void kernel_launch(void* const* d_in, const int* in_sizes, int n_in,
                              void* d_out, int out_size, void* d_ws, size_t ws_size,
                              hipStream_t stream) {
  const float* x    = (const float*)d_in[0];
  const float* kp_w = (const float*)d_in[1];
  const float* kp_b = (const float*)d_in[2];
  const float* so_w = (const float*)d_in[3];
  const float* so_b = (const float*)d_in[4];
  const float* mo_w = (const float*)d_in[5];
  const float* mo_b = (const float*)d_in[6];
  const float* lo_w = (const float*)d_in[7];
  const float* lo_b = (const float*)d_in[8];
  const float* ss_w = (const float*)d_in[9];
  const float* ss_b = (const float*)d_in[10];
  float* out = (float*)d_out;

  heads_kernel<<<dim3(338), dim3(256), 0, stream>>>(x, kp_w, kp_b, so_w, so_b,
                                                    mo_w, mo_b, lo_w, lo_b,
                                                    ss_w, ss_b);
  ksos_kernel<<<dim3(2048), dim3(256), 0, stream>>>(out);
  refine512_kernel<<<dim3(13, 26, 2), dim3(32, 16, 1), 0, stream>>>(out);
}

// Round 7
// 395.068 us; speedup vs baseline: 1.0955x; 1.0955x over previous
//
#include <hip/hip_runtime.h>
#include <math.h>

#define IMG 401
#define NKP 17
#define NMID 32
#define CCH 150   // coarse channels: 0-16 kp(sig) | 17-50 so | 51-114 mo | 115-148 lo | 149 ss(sig)

// output region element offsets (f32 elements)
#define OFF_KP   0ULL
#define OFF_SO   5467234ULL
#define OFF_MID  16401702ULL
#define OFF_LONG 36984230ULL
#define OFF_SS   47918698ULL
// total out_size = 48,240,300 f32

#define SCc (13.0f/401.0f)
#define C0c (13.0f/802.0f - 0.5f)

// statics: rewritten fully every call before being read
__device__ float  g_coarse[2 * 169 * CCH];
// field-planar pairs: [n][66 fields][169 cells] float2; fields 0-16=so,17-48=mo,49-65=lo
__device__ float2 g_pairs[2 * 66 * 169];

__constant__ int TO_KP_C[32] = {1,3,2,4,5,7,9,11,13,15,6,8,10,12,14,16,
                                0,1,0,2,0,5,7,5,11,13,0,6,8,6,12,14};

__device__ __forceinline__ void store2(float* p, float a, float b) {
  *reinterpret_cast<float2*>(p) = make_float2(a, b);   // 8B-aligned by construction
}

// ---------------- kernel 1: heads GEMM (x[338,2048] @ W -> coarse + pairs) ----------
__global__ __launch_bounds__(256)
void heads_kernel(const float* __restrict__ x,
                  const float* __restrict__ kp_w, const float* __restrict__ kp_b,
                  const float* __restrict__ so_w, const float* __restrict__ so_b,
                  const float* __restrict__ mo_w, const float* __restrict__ mo_b,
                  const float* __restrict__ lo_w, const float* __restrict__ lo_b,
                  const float* __restrict__ ss_w, const float* __restrict__ ss_b) {
  __shared__ float xs[2048];
  const int pix = blockIdx.x;                 // 0..337  (= n*169 + p)
  const float* xr = x + (size_t)pix * 2048;
  for (int t = threadIdx.x; t < 2048; t += 256) xs[t] = xr[t];
  __syncthreads();
  const int c = threadIdx.x;
  if (c >= CCH) return;
  const float* wptr; const float* bptr; int Ch, cc; bool sig = false;
  if (c < 17)       { wptr = kp_w; bptr = kp_b; Ch = 17; cc = c;       sig = true; }
  else if (c < 51)  { wptr = so_w; bptr = so_b; Ch = 34; cc = c - 17; }
  else if (c < 115) { wptr = mo_w; bptr = mo_b; Ch = 64; cc = c - 51; }
  else if (c < 149) { wptr = lo_w; bptr = lo_b; Ch = 34; cc = c - 115; }
  else              { wptr = ss_w; bptr = ss_b; Ch = 1;  cc = 0;       sig = true; }
  float acc = bptr[cc];
  const float* wp = wptr + cc;
  #pragma unroll 8
  for (int k = 0; k < 2048; ++k) acc = fmaf(xs[k], wp[k * Ch], acc);
  if (sig) acc = 1.0f / (1.0f + expf(-acc));
  g_coarse[(size_t)pix * CCH + c] = acc;
  if (c >= 17 && c < 149) {
    int rel = c - 17;
    int nn = pix / 169, pp = pix - nn * 169;
    ((float*)g_pairs)[(((size_t)nn * 66 + (rel >> 1)) * 169 + pp) * 2 + (rel & 1)] = acc;
  }
}

// ------------- fine-grid index -> coarse cell map (jax.image.resize bilinear, clamped) ----
__device__ __forceinline__ void cmapf(int j, int& i0, int& i1, float& f) {
  float s  = fmaf((float)j, SCc, C0c);
  float fl = floorf(s);
  f = s - fl;
  int a = (int)fl, b = a + 1;
  i0 = a < 0 ? 0 : (a > 12 ? 12 : a);
  i1 = b < 0 ? 0 : (b > 12 ? 12 : b);
}

__device__ __forceinline__ float2 blp4(const float2* __restrict__ F,
                                       int i00, int i01, int i10, int i11,
                                       float q00, float q01, float q10, float q11) {
  float2 a = F[i00], b = F[i01], c = F[i10], d = F[i11];
  return make_float2(q00 * a.x + q01 * b.x + q10 * c.x + q11 * d.x,
                     q00 * a.y + q01 * b.y + q10 * c.y + q11 * d.y);
}

struct Ctx { float wlo, whi, hlo, hhi, sw, sh; };

// ----- unified branch-free bilinear_sampler eval on resized field F (13x13 in LDS) -----
__device__ __forceinline__ float2 sampleU(const float2* __restrict__ F,
                                          float2 v, const Ctx& c) {
  float fx0 = floorf(v.x), fy0 = floorf(v.y);
  float dx = v.x - fx0,    dy = v.y - fy0;
  float ex = dx > 0.f ? 1.f : 0.f;
  float ey = dy > 0.f ? 1.f : 0.f;
  // border mask (exact integer arithmetic in f32): jx0<0 | jy0<0 | jx1>400 | jy1>400
  if (fx0 < c.wlo || fy0 < c.hlo || fx0 + ex > c.whi || fy0 + ey > c.hhi)
    return make_float2(0.f, 0.f);
  // coarse-space coords of the two fine x-corners / y-corners
  float s0 = fmaf(fx0, SCc, c.sw);
  float s1 = fmaf(ex,  SCc, s0);
  float t0 = fmaf(fy0, SCc, c.sh);
  float t1 = fmaf(ey,  SCc, t0);
  // clamp-extended cell contexts (exactly reproduces cmapf clamping)
  float Xc0 = fminf(fmaxf(s0, 0.f), 12.f), Xc1 = fminf(fmaxf(s1, 0.f), 12.f);
  float Yc0 = fminf(fmaxf(t0, 0.f), 12.f), Yc1 = fminf(fmaxf(t1, 0.f), 12.f);
  float cx0f = fminf(floorf(Xc0), 11.f), cx1f = fminf(floorf(Xc1), 11.f);
  float cy0f = fminf(floorf(Yc0), 11.f), cy1f = fminf(floorf(Yc1), 11.f);
  float u0 = Xc0 - cx0f, u1 = Xc1 - cx1f;
  float w0 = Yc0 - cy0f, w1 = Yc1 - cy1f;
  int cx0 = (int)cx0f, cx1 = (int)cx1f, cy0 = (int)cy0f, cy1 = (int)cy1f;
  // fold outer (dx,dy) corner weights into per-axis weights
  float gx = 1.f - dx, gy = 1.f - dy;
  float A0 = gx*(1.f-u0), A1 = gx*u0, A2 = dx*(1.f-u1), A3 = dx*u1;
  float B0 = gy*(1.f-w0), B1 = gy*w0, B2 = dy*(1.f-w1), B3 = dy*w1;
  int r0 = cy0*13, r1 = r0+13, r2 = cy1*13, r3 = r2+13;
  float ax = 0.f, ay = 0.f;
#define ROWC(rb, Bw) { \
    float2 p0 = F[rb+cx0], p1 = F[rb+cx0+1]; \
    float2 p2 = F[rb+cx1], p3 = F[rb+cx1+1]; \
    float rx = fmaf(A3,p3.x, fmaf(A2,p2.x, fmaf(A1,p1.x, A0*p0.x))); \
    float ry = fmaf(A3,p3.y, fmaf(A2,p2.y, fmaf(A1,p1.y, A0*p0.y))); \
    ax = fmaf(Bw, rx, ax); ay = fmaf(Bw, ry, ay); }
  ROWC(r0, B0) ROWC(r1, B1) ROWC(r2, B2) ROWC(r3, B3)
#undef ROWC
  return make_float2(ax, ay);
}

// ---------------- kernel 2: fused resize + refinement + all outputs ----------------------
__global__ __launch_bounds__(512, 6)
void refine512_kernel(float* __restrict__ out) {
  __shared__ float2 Sf[NKP * 169];
  __shared__ float2 Lf[NKP * 169];
  const int n = blockIdx.z;
  const int tid = threadIdx.y * 32 + threadIdx.x;
  for (int t = tid; t < NKP * 169; t += 512) {
    int k = t / 169, p = t - k * 169;
    Sf[t] = g_pairs[((size_t)n * 66 + k) * 169 + p];
    Lf[t] = g_pairs[((size_t)n * 66 + 49 + k) * 169 + p];
  }
  __syncthreads();
  const int w = blockIdx.x * 32 + threadIdx.x;
  const int h = blockIdx.y * 16 + threadIdx.y;
  if (w >= IMG || h >= IMG) return;

  int px0, px1, py0, py1; float pfx, pfy;
  cmapf(w, px0, px1, pfx);
  cmapf(h, py0, py1, pfy);
  const float q00 = (1.f-pfx)*(1.f-pfy), q01 = pfx*(1.f-pfy);
  const float q10 = (1.f-pfx)*pfy,       q11 = pfx*pfy;
  const int i00 = py0*13+px0, i01 = py0*13+px1, i10 = py1*13+px0, i11 = py1*13+px1;
  const size_t pix = ((size_t)n * IMG + h) * IMG + w;

  Ctx ctx;
  ctx.wlo = -(float)w;  ctx.whi = 400.f - (float)w;
  ctx.hlo = -(float)h;  ctx.hhi = 400.f - (float)h;
  ctx.sw  = fmaf((float)w, SCc, C0c);
  ctx.sh  = fmaf((float)h, SCc, C0c);

  // kp (17, sigmoid already applied) + ss from g_coarse (L2-broadcast reads)
  {
    const float* cb = g_coarse + (size_t)n * 169 * CCH;
    const float* c00 = cb + i00 * CCH; const float* c01 = cb + i01 * CCH;
    const float* c10 = cb + i10 * CCH; const float* c11 = cb + i11 * CCH;
    float* okp = out + OFF_KP + pix * 17;
    #pragma unroll
    for (int c = 0; c < 17; ++c)
      okp[c] = q00*c00[c] + q01*c01[c] + q10*c10[c] + q11*c11[c];
    out[OFF_SS + pix] = q00*c00[149] + q01*c01[149] + q10*c10[149] + q11*c11[149];
  }

  // so + long
  float* oso = out + OFF_SO + pix * 34;
  float* olg = out + OFF_LONG + pix * 34;
  for (int k = 0; k < NKP; ++k) {
    const float2* S = &Sf[k * 169];
    const float2* L = &Lf[k * 169];
    float2 sv = blp4(S, i00, i01, i10, i11, q00, q01, q10, q11);
    store2(oso + 2 * k, sv.x, sv.y);
    float2 b = blp4(L, i00, i01, i10, i11, q00, q01, q10, q11);
    float2 d;
    d = sampleU(L, b, ctx); b.x += d.x; b.y += d.y;
    d = sampleU(L, b, ctx); b.x += d.x; b.y += d.y;
    d = sampleU(S, b, ctx); b.x += d.x; b.y += d.y;
    d = sampleU(S, b, ctx); b.x += d.x; b.y += d.y;
    store2(olg + 2 * k, b.x, b.y);
  }

  // mid: 32 groups, 64 channels per pixel
  float* omd = out + OFF_MID + pix * 64;
  const float2* gmo = g_pairs + ((size_t)n * 66 + 17) * 169;
  for (int g = 0; g < NMID; ++g) {
    const float2* G = gmo + (size_t)g * 169;
    float2 e00 = G[i00], e01 = G[i01], e10 = G[i10], e11 = G[i11];
    float2 b = make_float2(q00*e00.x + q01*e01.x + q10*e10.x + q11*e11.x,
                           q00*e00.y + q01*e01.y + q10*e10.y + q11*e11.y);
    const float2* S = &Sf[TO_KP_C[g] * 169];
    float2 d;
    d = sampleU(S, b, ctx); b.x += d.x; b.y += d.y;
    d = sampleU(S, b, ctx); b.x += d.x; b.y += d.y;
    store2(omd + 2 * g, b.x, b.y);
  }
}

extern "C" void kernel_launch(void* const* d_in, const int* in_sizes, int n_in,
                              void* d_out, int out_size, void* d_ws, size_t ws_size,
                              hipStream_t stream) {
  const float* x    = (const float*)d_in[0];
  const float* kp_w = (const float*)d_in[1];
  const float* kp_b = (const float*)d_in[2];
  const float* so_w = (const float*)d_in[3];
  const float* so_b = (const float*)d_in[4];
  const float* mo_w = (const float*)d_in[5];
  const float* mo_b = (const float*)d_in[6];
  const float* lo_w = (const float*)d_in[7];
  const float* lo_b = (const float*)d_in[8];
  const float* ss_w = (const float*)d_in[9];
  const float* ss_b = (const float*)d_in[10];
  float* out = (float*)d_out;

  heads_kernel<<<dim3(338), dim3(256), 0, stream>>>(x, kp_w, kp_b, so_w, so_b,
                                                    mo_w, mo_b, lo_w, lo_b,
                                                    ss_w, ss_b);
  refine512_kernel<<<dim3(13, 26, 2), dim3(32, 16, 1), 0, stream>>>(out);
}

// Round 8
// 252.540 us; speedup vs baseline: 1.7138x; 1.5644x over previous
//
#include <hip/hip_runtime.h>
#include <math.h>

#define IMG 401
#define NKP 17
#define NMID 32
#define CCH 150   // coarse channels: 0-16 kp(sig) | 17-50 so | 51-114 mo | 115-148 lo | 149 ss(sig)

// output region element offsets (f32 elements)
#define OFF_KP   0ULL
#define OFF_SO   5467234ULL
#define OFF_MID  16401702ULL
#define OFF_LONG 36984230ULL
#define OFF_SS   47918698ULL
// total out_size = 48,240,300 f32

#define SCc (13.0f/401.0f)
#define C0c (13.0f/802.0f - 0.5f)

// statics: rewritten fully every call before being read
__device__ float  g_coarse[2 * 169 * CCH];
// field-planar pairs: [n][66 fields][169 cells] float2; fields 0-16=so,17-48=mo,49-65=lo
__device__ float2 g_pairs[2 * 66 * 169];

__constant__ int TO_KP_C[32] = {1,3,2,4,5,7,9,11,13,15,6,8,10,12,14,16,
                                0,1,0,2,0,5,7,5,11,13,0,6,8,6,12,14};

// ---------------- kernel 1: heads GEMM (x[338,2048] @ W -> coarse + pairs) ----------
__global__ __launch_bounds__(256)
void heads_kernel(const float* __restrict__ x,
                  const float* __restrict__ kp_w, const float* __restrict__ kp_b,
                  const float* __restrict__ so_w, const float* __restrict__ so_b,
                  const float* __restrict__ mo_w, const float* __restrict__ mo_b,
                  const float* __restrict__ lo_w, const float* __restrict__ lo_b,
                  const float* __restrict__ ss_w, const float* __restrict__ ss_b) {
  __shared__ float xs[2048];
  const int pix = blockIdx.x;                 // 0..337  (= n*169 + p)
  const float* xr = x + (size_t)pix * 2048;
  for (int t = threadIdx.x; t < 2048; t += 256) xs[t] = xr[t];
  __syncthreads();
  const int c = threadIdx.x;
  if (c >= CCH) return;
  const float* wptr; const float* bptr; int Ch, cc; bool sig = false;
  if (c < 17)       { wptr = kp_w; bptr = kp_b; Ch = 17; cc = c;       sig = true; }
  else if (c < 51)  { wptr = so_w; bptr = so_b; Ch = 34; cc = c - 17; }
  else if (c < 115) { wptr = mo_w; bptr = mo_b; Ch = 64; cc = c - 51; }
  else if (c < 149) { wptr = lo_w; bptr = lo_b; Ch = 34; cc = c - 115; }
  else              { wptr = ss_w; bptr = ss_b; Ch = 1;  cc = 0;       sig = true; }
  float acc = bptr[cc];
  const float* wp = wptr + cc;
  #pragma unroll 64
  for (int k = 0; k < 2048; ++k) acc = fmaf(xs[k], wp[k * Ch], acc);
  if (sig) acc = 1.0f / (1.0f + expf(-acc));
  g_coarse[(size_t)pix * CCH + c] = acc;
  if (c >= 17 && c < 149) {
    int rel = c - 17;
    int nn = pix / 169, pp = pix - nn * 169;
    ((float*)g_pairs)[(((size_t)nn * 66 + (rel >> 1)) * 169 + pp) * 2 + (rel & 1)] = acc;
  }
}

// ------------- fine-grid index -> coarse cell map (jax.image.resize bilinear, clamped) ----
__device__ __forceinline__ void cmapf(int j, int& i0, int& i1, float& f) {
  float s  = fmaf((float)j, SCc, C0c);
  float fl = floorf(s);
  f = s - fl;
  int a = (int)fl, b = a + 1;
  i0 = a < 0 ? 0 : (a > 12 ? 12 : a);
  i1 = b < 0 ? 0 : (b > 12 ? 12 : b);
}

__device__ __forceinline__ float2 blp4(const float2* __restrict__ F,
                                       int i00, int i01, int i10, int i11,
                                       float q00, float q01, float q10, float q11) {
  float2 a = F[i00], b = F[i01], c = F[i10], d = F[i11];
  return make_float2(q00 * a.x + q01 * b.x + q10 * c.x + q11 * d.x,
                     q00 * a.y + q01 * b.y + q10 * c.y + q11 * d.y);
}

struct Ctx { float wlo, whi, hlo, hhi, sw, sh; };

// ----- unified branch-free bilinear_sampler eval on resized field F (13x13 in LDS) -----
__device__ __forceinline__ float2 sampleU(const float2* __restrict__ F,
                                          float2 v, const Ctx& c) {
  float fx0 = floorf(v.x), fy0 = floorf(v.y);
  float dx = v.x - fx0,    dy = v.y - fy0;
  float ex = dx > 0.f ? 1.f : 0.f;
  float ey = dy > 0.f ? 1.f : 0.f;
  if (fx0 < c.wlo || fy0 < c.hlo || fx0 + ex > c.whi || fy0 + ey > c.hhi)
    return make_float2(0.f, 0.f);
  float s0 = fmaf(fx0, SCc, c.sw);
  float s1 = fmaf(ex,  SCc, s0);
  float t0 = fmaf(fy0, SCc, c.sh);
  float t1 = fmaf(ey,  SCc, t0);
  float Xc0 = fminf(fmaxf(s0, 0.f), 12.f), Xc1 = fminf(fmaxf(s1, 0.f), 12.f);
  float Yc0 = fminf(fmaxf(t0, 0.f), 12.f), Yc1 = fminf(fmaxf(t1, 0.f), 12.f);
  float cx0f = fminf(floorf(Xc0), 11.f), cx1f = fminf(floorf(Xc1), 11.f);
  float cy0f = fminf(floorf(Yc0), 11.f), cy1f = fminf(floorf(Yc1), 11.f);
  float u0 = Xc0 - cx0f, u1 = Xc1 - cx1f;
  float w0 = Yc0 - cy0f, w1 = Yc1 - cy1f;
  int cx0 = (int)cx0f, cx1 = (int)cx1f, cy0 = (int)cy0f, cy1 = (int)cy1f;
  float gx = 1.f - dx, gy = 1.f - dy;
  float A0 = gx*(1.f-u0), A1 = gx*u0, A2 = dx*(1.f-u1), A3 = dx*u1;
  float B0 = gy*(1.f-w0), B1 = gy*w0, B2 = dy*(1.f-w1), B3 = dy*w1;
  int r0 = cy0*13, r1 = r0+13, r2 = cy1*13, r3 = r2+13;
  float ax = 0.f, ay = 0.f;
#define ROWC(rb, Bw) { \
    float2 p0 = F[rb+cx0], p1 = F[rb+cx0+1]; \
    float2 p2 = F[rb+cx1], p3 = F[rb+cx1+1]; \
    float rx = fmaf(A3,p3.x, fmaf(A2,p2.x, fmaf(A1,p1.x, A0*p0.x))); \
    float ry = fmaf(A3,p3.y, fmaf(A2,p2.y, fmaf(A1,p1.y, A0*p0.y))); \
    ax = fmaf(Bw, rx, ax); ay = fmaf(Bw, ry, ay); }
  ROWC(r0, B0) ROWC(r1, B1) ROWC(r2, B2) ROWC(r3, B3)
#undef ROWC
  return make_float2(ax, ay);
}

// ----- per-wave LDS-transpose flush: lane-dense global stores -----------------------------
// stg layout: addr = 33*(lane>>2) + 8*(lane&3) + cc  (skewed; 2-way bank max = free)
template<int NC>
__device__ __forceinline__ void flushW(float* stg, const float* buf, int lane,
                                       float* gA, float* gB, int CH, int c0,
                                       int nvx, bool vA, bool vB) {
  constexpr int LOG = (NC == 8 ? 3 : (NC == 2 ? 1 : 0));
  const int wa = 33*(lane>>2) + 8*(lane&3);
#pragma unroll
  for (int cc = 0; cc < NC; ++cc) stg[wa + cc] = buf[cc];
  const int l32 = lane & 31;
  const bool isB = lane >= 32;
  float* g = isB ? gB : gA;
  const bool vrow = isB ? vB : vA;
#pragma unroll
  for (int j = 0; j < NC; ++j) {
    int f = j*32 + l32;
    int px = f >> LOG;
    int cc = f & (NC - 1);
    int lsrc = (isB ? 32 : 0) + px;
    float v = stg[33*(lsrc>>2) + 8*(lsrc&3) + cc];
    if (vrow && px < nvx) g[px*CH + c0 + cc] = v;
  }
}

// ---------------- kernel 2: fused resize + refinement + all outputs ----------------------
__global__ __launch_bounds__(512, 2)
void refine512_kernel(float* __restrict__ out) {
  __shared__ float2 Sf[NKP * 169];
  __shared__ float2 Lf[NKP * 169];
  __shared__ float  stg[8][528];
  const int n = blockIdx.z;
  const int tid = threadIdx.y * 32 + threadIdx.x;
  for (int t = tid; t < NKP * 169; t += 512) {
    int k = t / 169, p = t - k * 169;
    Sf[t] = g_pairs[((size_t)n * 66 + k) * 169 + p];
    Lf[t] = g_pairs[((size_t)n * 66 + 49 + k) * 169 + p];
  }
  __syncthreads();

  const int lane = tid & 63;
  float* stgW = stg[tid >> 6];
  const int w0 = blockIdx.x * 32;
  const int w  = w0 + threadIdx.x;
  const int h  = blockIdx.y * 16 + threadIdx.y;
  const int hA = blockIdx.y * 16 + (threadIdx.y & ~1);
  const int hB = hA + 1;
  const bool vA = hA < IMG, vB = hB < IMG;
  const int nvx = min(32, IMG - w0);
  const size_t pixA = ((size_t)n * IMG + hA) * IMG + w0;
  const size_t pixB = pixA + IMG;

  int px0, px1, py0, py1; float pfx, pfy;
  cmapf(w, px0, px1, pfx);
  cmapf(h, py0, py1, pfy);
  const float q00 = (1.f-pfx)*(1.f-pfy), q01 = pfx*(1.f-pfy);
  const float q10 = (1.f-pfx)*pfy,       q11 = pfx*pfy;
  const int i00 = py0*13+px0, i01 = py0*13+px1, i10 = py1*13+px0, i11 = py1*13+px1;

  Ctx ctx;
  ctx.wlo = -(float)w;  ctx.whi = 400.f - (float)w;
  ctx.hlo = -(float)h;  ctx.hhi = 400.f - (float)h;
  ctx.sw  = fmaf((float)w, SCc, C0c);
  ctx.sh  = fmaf((float)h, SCc, C0c);

  float buf[8];

  // ---- kp (17 ch) + ss, from g_coarse (L1/L2-broadcast reads) ----
  {
    const float* cb  = g_coarse + (size_t)n * 169 * CCH;
    const float* c00 = cb + i00 * CCH; const float* c01 = cb + i01 * CCH;
    const float* c10 = cb + i10 * CCH; const float* c11 = cb + i11 * CCH;
    float* gA = out + OFF_KP + pixA * 17;
    float* gB = out + OFF_KP + pixB * 17;
    for (int c0 = 0; c0 < 16; c0 += 8) {
      #pragma unroll
      for (int cc = 0; cc < 8; ++cc) {
        int c = c0 + cc;
        buf[cc] = q00*c00[c] + q01*c01[c] + q10*c10[c] + q11*c11[c];
      }
      flushW<8>(stgW, buf, lane, gA, gB, 17, c0, nvx, vA, vB);
    }
    buf[0] = q00*c00[16] + q01*c01[16] + q10*c10[16] + q11*c11[16];
    flushW<1>(stgW, buf, lane, gA, gB, 17, 16, nvx, vA, vB);
    // ss: naturally lane-contiguous store
    float sv = q00*c00[149] + q01*c01[149] + q10*c10[149] + q11*c11[149];
    if (w < IMG && h < IMG)
      out[OFF_SS + ((size_t)n * IMG + h) * IMG + w] = sv;
  }

  // ---- so + long (34 ch each) ----
  {
    float* gsA = out + OFF_SO + pixA * 34;  float* gsB = out + OFF_SO + pixB * 34;
    float* glA = out + OFF_LONG + pixA * 34; float* glB = out + OFF_LONG + pixB * 34;
    float bufL[8];
    for (int kc = 0; kc < 4; ++kc) {
      #pragma unroll
      for (int ke = 0; ke < 4; ++ke) {
        int k = kc*4 + ke;
        const float2* S = &Sf[k * 169];
        const float2* L = &Lf[k * 169];
        float2 sv = blp4(S, i00, i01, i10, i11, q00, q01, q10, q11);
        buf[2*ke] = sv.x; buf[2*ke+1] = sv.y;
        float2 b = blp4(L, i00, i01, i10, i11, q00, q01, q10, q11);
        float2 d;
        d = sampleU(L, b, ctx); b.x += d.x; b.y += d.y;
        d = sampleU(L, b, ctx); b.x += d.x; b.y += d.y;
        d = sampleU(S, b, ctx); b.x += d.x; b.y += d.y;
        d = sampleU(S, b, ctx); b.x += d.x; b.y += d.y;
        bufL[2*ke] = b.x; bufL[2*ke+1] = b.y;
      }
      flushW<8>(stgW, buf,  lane, gsA, gsB, 34, kc*8, nvx, vA, vB);
      flushW<8>(stgW, bufL, lane, glA, glB, 34, kc*8, nvx, vA, vB);
    }
    { // k = 16 remainder
      const float2* S = &Sf[16 * 169];
      const float2* L = &Lf[16 * 169];
      float2 sv = blp4(S, i00, i01, i10, i11, q00, q01, q10, q11);
      buf[0] = sv.x; buf[1] = sv.y;
      float2 b = blp4(L, i00, i01, i10, i11, q00, q01, q10, q11);
      float2 d;
      d = sampleU(L, b, ctx); b.x += d.x; b.y += d.y;
      d = sampleU(L, b, ctx); b.x += d.x; b.y += d.y;
      d = sampleU(S, b, ctx); b.x += d.x; b.y += d.y;
      d = sampleU(S, b, ctx); b.x += d.x; b.y += d.y;
      bufL[0] = b.x; bufL[1] = b.y;
      flushW<2>(stgW, buf,  lane, gsA, gsB, 34, 32, nvx, vA, vB);
      flushW<2>(stgW, bufL, lane, glA, glB, 34, 32, nvx, vA, vB);
    }
  }

  // ---- mid (64 ch) ----
  {
    float* gA = out + OFF_MID + pixA * 64;
    float* gB = out + OFF_MID + pixB * 64;
    const float2* gmo = g_pairs + ((size_t)n * 66 + 17) * 169;
    for (int gc = 0; gc < 8; ++gc) {
      #pragma unroll
      for (int ge = 0; ge < 4; ++ge) {
        int g = gc*4 + ge;
        const float2* G = gmo + (size_t)g * 169;
        float2 e00 = G[i00], e01 = G[i01], e10 = G[i10], e11 = G[i11];
        float2 b = make_float2(q00*e00.x + q01*e01.x + q10*e10.x + q11*e11.x,
                               q00*e00.y + q01*e01.y + q10*e10.y + q11*e11.y);
        const float2* S = &Sf[TO_KP_C[g] * 169];
        float2 d;
        d = sampleU(S, b, ctx); b.x += d.x; b.y += d.y;
        d = sampleU(S, b, ctx); b.x += d.x; b.y += d.y;
        buf[2*ge] = b.x; buf[2*ge+1] = b.y;
      }
      flushW<8>(stgW, buf, lane, gA, gB, 64, gc*8, nvx, vA, vB);
    }
  }
}

extern "C" void kernel_launch(void* const* d_in, const int* in_sizes, int n_in,
                              void* d_out, int out_size, void* d_ws, size_t ws_size,
                              hipStream_t stream) {
  const float* x    = (const float*)d_in[0];
  const float* kp_w = (const float*)d_in[1];
  const float* kp_b = (const float*)d_in[2];
  const float* so_w = (const float*)d_in[3];
  const float* so_b = (const float*)d_in[4];
  const float* mo_w = (const float*)d_in[5];
  const float* mo_b = (const float*)d_in[6];
  const float* lo_w = (const float*)d_in[7];
  const float* lo_b = (const float*)d_in[8];
  const float* ss_w = (const float*)d_in[9];
  const float* ss_b = (const float*)d_in[10];
  float* out = (float*)d_out;

  heads_kernel<<<dim3(338), dim3(256), 0, stream>>>(x, kp_w, kp_b, so_w, so_b,
                                                    mo_w, mo_b, lo_w, lo_b,
                                                    ss_w, ss_b);
  refine512_kernel<<<dim3(13, 26, 2), dim3(32, 16, 1), 0, stream>>>(out);
}

// Round 9
// 233.378 us; speedup vs baseline: 1.8545x; 1.0821x over previous
//
#include <hip/hip_runtime.h>
#include <math.h>

#define IMG 401
#define NKP 17
#define NMID 32
#define CCH 150   // coarse channels: 0-16 kp(sig) | 17-50 so | 51-114 mo | 115-148 lo | 149 ss(sig)

// output region element offsets (f32 elements)
#define OFF_KP   0ULL
#define OFF_SO   5467234ULL
#define OFF_MID  16401702ULL
#define OFF_LONG 36984230ULL
#define OFF_SS   47918698ULL
// total out_size = 48,240,300 f32

#define SCc (13.0f/401.0f)
#define C0c (13.0f/802.0f - 0.5f)

// statics: rewritten fully every call before being read
__device__ float  g_coarse[2 * 169 * CCH];
// field-planar pairs: [n][66 fields][169 cells] float2; fields 0-16=so,17-48=mo,49-65=lo
__device__ float2 g_pairs[2 * 66 * 169];

__constant__ int TO_KP_C[32] = {1,3,2,4,5,7,9,11,13,15,6,8,10,12,14,16,
                                0,1,0,2,0,5,7,5,11,13,0,6,8,6,12,14};

__device__ __forceinline__ void store2(float* p, float a, float b) {
  *reinterpret_cast<float2*>(p) = make_float2(a, b);   // 8B-aligned by construction
}

// ---------------- kernel 1: heads GEMM (x[338,2048] @ W -> coarse + pairs) ----------
__global__ __launch_bounds__(256)
void heads_kernel(const float* __restrict__ x,
                  const float* __restrict__ kp_w, const float* __restrict__ kp_b,
                  const float* __restrict__ so_w, const float* __restrict__ so_b,
                  const float* __restrict__ mo_w, const float* __restrict__ mo_b,
                  const float* __restrict__ lo_w, const float* __restrict__ lo_b,
                  const float* __restrict__ ss_w, const float* __restrict__ ss_b) {
  __shared__ float xs[2048];
  const int pix = blockIdx.x;                 // 0..337  (= n*169 + p)
  const float* xr = x + (size_t)pix * 2048;
  for (int t = threadIdx.x; t < 2048; t += 256) xs[t] = xr[t];
  __syncthreads();
  const int c = threadIdx.x;
  if (c >= CCH) return;
  const float* wptr; const float* bptr; int Ch, cc; bool sig = false;
  if (c < 17)       { wptr = kp_w; bptr = kp_b; Ch = 17; cc = c;       sig = true; }
  else if (c < 51)  { wptr = so_w; bptr = so_b; Ch = 34; cc = c - 17; }
  else if (c < 115) { wptr = mo_w; bptr = mo_b; Ch = 64; cc = c - 51; }
  else if (c < 149) { wptr = lo_w; bptr = lo_b; Ch = 34; cc = c - 115; }
  else              { wptr = ss_w; bptr = ss_b; Ch = 1;  cc = 0;       sig = true; }
  float acc = bptr[cc];
  const float* wp = wptr + cc;
  #pragma unroll 64
  for (int k = 0; k < 2048; ++k) acc = fmaf(xs[k], wp[k * Ch], acc);
  if (sig) acc = 1.0f / (1.0f + expf(-acc));
  g_coarse[(size_t)pix * CCH + c] = acc;
  if (c >= 17 && c < 149) {
    int rel = c - 17;
    int nn = pix / 169, pp = pix - nn * 169;
    ((float*)g_pairs)[(((size_t)nn * 66 + (rel >> 1)) * 169 + pp) * 2 + (rel & 1)] = acc;
  }
}

// ------------- fine-grid index -> coarse cell map (jax.image.resize bilinear, clamped) ----
__device__ __forceinline__ void cmapf(int j, int& i0, int& i1, float& f) {
  float s  = fmaf((float)j, SCc, C0c);
  float fl = floorf(s);
  f = s - fl;
  int a = (int)fl, b = a + 1;
  i0 = a < 0 ? 0 : (a > 12 ? 12 : a);
  i1 = b < 0 ? 0 : (b > 12 ? 12 : b);
}

__device__ __forceinline__ float2 blp4(const float2* __restrict__ F,
                                       int i00, int i01, int i10, int i11,
                                       float q00, float q01, float q10, float q11) {
  float2 a = F[i00], b = F[i01], c = F[i10], d = F[i11];
  return make_float2(q00 * a.x + q01 * b.x + q10 * c.x + q11 * d.x,
                     q00 * a.y + q01 * b.y + q10 * c.y + q11 * d.y);
}

struct Ctx { float wlo, whi, hlo, hhi, sw, sh; };

// ----- unified branch-free bilinear_sampler eval on resized field F (13x13) -----
__device__ __forceinline__ float2 sampleU(const float2* __restrict__ F,
                                          float2 v, const Ctx& c) {
  float fx0 = floorf(v.x), fy0 = floorf(v.y);
  float dx = v.x - fx0,    dy = v.y - fy0;
  float ex = dx > 0.f ? 1.f : 0.f;
  float ey = dy > 0.f ? 1.f : 0.f;
  if (fx0 < c.wlo || fy0 < c.hlo || fx0 + ex > c.whi || fy0 + ey > c.hhi)
    return make_float2(0.f, 0.f);
  float s0 = fmaf(fx0, SCc, c.sw);
  float s1 = fmaf(ex,  SCc, s0);
  float t0 = fmaf(fy0, SCc, c.sh);
  float t1 = fmaf(ey,  SCc, t0);
  float Xc0 = fminf(fmaxf(s0, 0.f), 12.f), Xc1 = fminf(fmaxf(s1, 0.f), 12.f);
  float Yc0 = fminf(fmaxf(t0, 0.f), 12.f), Yc1 = fminf(fmaxf(t1, 0.f), 12.f);
  float cx0f = fminf(floorf(Xc0), 11.f), cx1f = fminf(floorf(Xc1), 11.f);
  float cy0f = fminf(floorf(Yc0), 11.f), cy1f = fminf(floorf(Yc1), 11.f);
  float u0 = Xc0 - cx0f, u1 = Xc1 - cx1f;
  float w0 = Yc0 - cy0f, w1 = Yc1 - cy1f;
  int cx0 = (int)cx0f, cx1 = (int)cx1f, cy0 = (int)cy0f, cy1 = (int)cy1f;
  float gx = 1.f - dx, gy = 1.f - dy;
  float A0 = gx*(1.f-u0), A1 = gx*u0, A2 = dx*(1.f-u1), A3 = dx*u1;
  float B0 = gy*(1.f-w0), B1 = gy*w0, B2 = dy*(1.f-w1), B3 = dy*w1;
  int r0 = cy0*13, r1 = r0+13, r2 = cy1*13, r3 = r2+13;
  float ax = 0.f, ay = 0.f;
#define ROWC(rb, Bw) { \
    float2 p0 = F[rb+cx0], p1 = F[rb+cx0+1]; \
    float2 p2 = F[rb+cx1], p3 = F[rb+cx1+1]; \
    float rx = fmaf(A3,p3.x, fmaf(A2,p2.x, fmaf(A1,p1.x, A0*p0.x))); \
    float ry = fmaf(A3,p3.y, fmaf(A2,p2.y, fmaf(A1,p1.y, A0*p0.y))); \
    ax = fmaf(Bw, rx, ax); ay = fmaf(Bw, ry, ay); }
  ROWC(r0, B0) ROWC(r1, B1) ROWC(r2, B2) ROWC(r3, B3)
#undef ROWC
  return make_float2(ax, ay);
}

// ----- per-item pixel context ------------------------------------------------------------
struct PixCtx {
  float q00, q01, q10, q11;
  int   i00, i01, i10, i11;
  Ctx   ctx;
  bool  valid;
  size_t pix;
};

__device__ __forceinline__ PixCtx mkpix(int n, int w, int h) {
  PixCtx P;
  P.valid = (w < IMG) && (h < IMG);
  int px0, px1, py0, py1; float fx, fy;
  cmapf(w, px0, px1, fx);
  cmapf(h, py0, py1, fy);
  P.q00 = (1.f-fx)*(1.f-fy); P.q01 = fx*(1.f-fy);
  P.q10 = (1.f-fx)*fy;       P.q11 = fx*fy;
  P.i00 = py0*13+px0; P.i01 = py0*13+px1; P.i10 = py1*13+px0; P.i11 = py1*13+px1;
  P.ctx.wlo = -(float)w;  P.ctx.whi = 400.f - (float)w;
  P.ctx.hlo = -(float)h;  P.ctx.hhi = 400.f - (float)h;
  P.ctx.sw  = fmaf((float)w, SCc, C0c);
  P.ctx.sh  = fmaf((float)h, SCc, C0c);
  P.pix = ((size_t)n * IMG + h) * IMG + w;
  return P;
}

// ---------------- kernel 2: element-remapped fused resize + refinement -------------------
// Work item = output element/pair, so every global store instruction is lane-dense.
__global__ __launch_bounds__(512, 6)
void refine512_kernel(float* __restrict__ out) {
  __shared__ float2 Sf[NKP * 169];
  __shared__ float2 Lf[NKP * 169];
  const int n = blockIdx.z;
  const int tid = threadIdx.x;
  const int w0 = blockIdx.x * 32, h0 = blockIdx.y * 16;

  {
    const float2* gS = g_pairs + (size_t)n * 66 * 169;
    const float2* gL = g_pairs + ((size_t)n * 66 + 49) * 169;
    for (int t = tid; t < NKP * 169; t += 512) { Sf[t] = gS[t]; Lf[t] = gL[t]; }
  }

  const float* cb = g_coarse + (size_t)n * 169 * CCH;

  // ---- kp sweep (no LDS dependency; runs before barrier): 16*32*17 = 8704 floats ----
  for (int it = 0; it < 17; ++it) {
    int f = it * 512 + tid;
    int r = f / 544, rem = f - r * 544;
    int px = rem / 17, c = rem - px * 17;
    PixCtx P = mkpix(n, w0 + px, h0 + r);
    if (P.valid) {
      float v = P.q00*cb[P.i00*CCH+c] + P.q01*cb[P.i01*CCH+c]
              + P.q10*cb[P.i10*CCH+c] + P.q11*cb[P.i11*CCH+c];
      out[OFF_KP + P.pix * 17 + c] = v;
    }
  }
  // ---- ss sweep: 16*32 = 512 floats ----
  {
    int r = tid >> 5, px = tid & 31;
    PixCtx P = mkpix(n, w0 + px, h0 + r);
    if (P.valid) {
      out[OFF_SS + P.pix] =
          P.q00*cb[P.i00*CCH+149] + P.q01*cb[P.i01*CCH+149]
        + P.q10*cb[P.i10*CCH+149] + P.q11*cb[P.i11*CCH+149];
    }
  }

  __syncthreads();

  // ---- so + long sweep: item = (row, px, k); 16*32*17 = 8704 pairs ----
  for (int it = 0; it < 17; ++it) {
    int f = it * 512 + tid;
    int r = f / 544, rem = f - r * 544;
    int px = rem / 17, k = rem - px * 17;
    PixCtx P = mkpix(n, w0 + px, h0 + r);
    const float2* S = &Sf[k * 169];
    const float2* L = &Lf[k * 169];
    float2 sv = blp4(S, P.i00, P.i01, P.i10, P.i11, P.q00, P.q01, P.q10, P.q11);
    float2 b  = blp4(L, P.i00, P.i01, P.i10, P.i11, P.q00, P.q01, P.q10, P.q11);
    float2 d;
    d = sampleU(L, b, P.ctx); b.x += d.x; b.y += d.y;
    d = sampleU(L, b, P.ctx); b.x += d.x; b.y += d.y;
    d = sampleU(S, b, P.ctx); b.x += d.x; b.y += d.y;
    d = sampleU(S, b, P.ctx); b.x += d.x; b.y += d.y;
    if (P.valid) {
      store2(out + OFF_SO   + P.pix * 34 + 2 * k, sv.x, sv.y);
      store2(out + OFF_LONG + P.pix * 34 + 2 * k, b.x, b.y);
    }
  }

  // ---- mid sweep: item = (row, px, g); 16*32*32 = 16384 pairs ----
  const float2* gmo = g_pairs + ((size_t)n * 66 + 17) * 169;
  for (int it = 0; it < 32; ++it) {
    int f = it * 512 + tid;
    int r = f >> 10, rem = f & 1023;
    int px = rem >> 5, g = rem & 31;
    PixCtx P = mkpix(n, w0 + px, h0 + r);
    const float2* G = gmo + (size_t)g * 169;
    float2 e00 = G[P.i00], e01 = G[P.i01], e10 = G[P.i10], e11 = G[P.i11];
    float2 b = make_float2(P.q00*e00.x + P.q01*e01.x + P.q10*e10.x + P.q11*e11.x,
                           P.q00*e00.y + P.q01*e01.y + P.q10*e10.y + P.q11*e11.y);
    const float2* S = &Sf[TO_KP_C[g] * 169];
    float2 d;
    d = sampleU(S, b, P.ctx); b.x += d.x; b.y += d.y;
    d = sampleU(S, b, P.ctx); b.x += d.x; b.y += d.y;
    if (P.valid) store2(out + OFF_MID + P.pix * 64 + 2 * g, b.x, b.y);
  }
}

extern "C" void kernel_launch(void* const* d_in, const int* in_sizes, int n_in,
                              void* d_out, int out_size, void* d_ws, size_t ws_size,
                              hipStream_t stream) {
  const float* x    = (const float*)d_in[0];
  const float* kp_w = (const float*)d_in[1];
  const float* kp_b = (const float*)d_in[2];
  const float* so_w = (const float*)d_in[3];
  const float* so_b = (const float*)d_in[4];
  const float* mo_w = (const float*)d_in[5];
  const float* mo_b = (const float*)d_in[6];
  const float* lo_w = (const float*)d_in[7];
  const float* lo_b = (const float*)d_in[8];
  const float* ss_w = (const float*)d_in[9];
  const float* ss_b = (const float*)d_in[10];
  float* out = (float*)d_out;

  heads_kernel<<<dim3(338), dim3(256), 0, stream>>>(x, kp_w, kp_b, so_w, so_b,
                                                    mo_w, mo_b, lo_w, lo_b,
                                                    ss_w, ss_b);
  refine512_kernel<<<dim3(13, 26, 2), dim3(512), 0, stream>>>(out);
}